// Round 1
// baseline (86.624 us; speedup 1.0000x reference)
//
#include <hip/hip_runtime.h>
#include <cstddef>

#define Hn 1024
#define Vn 32000
#define Sn 4096

__device__ __forceinline__ float wave_reduce_sum(float v) {
#pragma unroll
    for (int o = 32; o > 0; o >>= 1) v += __shfl_down(v, o, 64);
    return v;
}

// ws layout (floats):
// [0,1024)      h            (c2 = [h, context] contiguous)
// [1024,2048)   context
// [2048,3072)   v = attn_w^T h
// [3072,7168)   scores
// [7168,11264)  attn
// [11264,44032) partials (32 x 1024)

// ---------------- K1: GRU cell -> h ----------------
__global__ __launch_bounds__(256) void k_gru(const int* __restrict__ word,
                                             const float* __restrict__ emb,
                                             const float* __restrict__ h0,
                                             const float* __restrict__ w_ih,
                                             const float* __restrict__ w_hh,
                                             const float* __restrict__ b_ih,
                                             const float* __restrict__ b_hh,
                                             float* __restrict__ ws_h,
                                             float* __restrict__ out_h)
{
    const int k = blockIdx.x;   // output element 0..1023
    const int t = threadIdx.x;  // 0..255, each owns one float4 (4 columns)
    const float* x = emb + (size_t)word[0] * Hn;
    const float4 xv = ((const float4*)x)[t];
    const float4 hv = ((const float4*)h0)[t];

    float acc[6];
    const float* rows[6] = {
        w_ih + (size_t)k * Hn, w_ih + (size_t)(k + Hn) * Hn, w_ih + (size_t)(k + 2 * Hn) * Hn,
        w_hh + (size_t)k * Hn, w_hh + (size_t)(k + Hn) * Hn, w_hh + (size_t)(k + 2 * Hn) * Hn
    };
#pragma unroll
    for (int g = 0; g < 6; ++g) {
        const float4 w = ((const float4*)rows[g])[t];
        const float4 vv = (g < 3) ? xv : hv;
        acc[g] = w.x * vv.x + w.y * vv.y + w.z * vv.z + w.w * vv.w;
    }

    __shared__ float red[6][4];
    const int wv = t >> 6, lane = t & 63;
#pragma unroll
    for (int g = 0; g < 6; ++g) {
        const float s = wave_reduce_sum(acc[g]);
        if (lane == 0) red[g][wv] = s;
    }
    __syncthreads();
    if (t == 0) {
        float g0 = red[0][0] + red[0][1] + red[0][2] + red[0][3] + b_ih[k];
        float g1 = red[1][0] + red[1][1] + red[1][2] + red[1][3] + b_ih[k + Hn];
        float g2 = red[2][0] + red[2][1] + red[2][2] + red[2][3] + b_ih[k + 2 * Hn];
        float g3 = red[3][0] + red[3][1] + red[3][2] + red[3][3] + b_hh[k];
        float g4 = red[4][0] + red[4][1] + red[4][2] + red[4][3] + b_hh[k + Hn];
        float g5 = red[5][0] + red[5][1] + red[5][2] + red[5][3] + b_hh[k + 2 * Hn];
        float r = 1.f / (1.f + expf(-(g0 + g3)));
        float z = 1.f / (1.f + expf(-(g1 + g4)));
        float n = tanhf(g2 + r * g5);
        float hk = (1.f - z) * n + z * h0[k];
        ws_h[k]  = hk;
        out_h[k] = hk;
    }
}

// ---------------- K2: v = attn_w^T h ----------------
__global__ __launch_bounds__(256) void k_attnv(const float* __restrict__ attn_w,
                                               const float* __restrict__ ws_h,
                                               float* __restrict__ v)
{
    const int t = threadIdx.x;
    const int tj = t >> 4;                 // 0..15 row-group
    const int tk = t & 15;                 // 0..15 column within block
    const int k = blockIdx.x * 16 + tk;
    float acc = 0.f;
    for (int j = tj; j < Hn; j += 16)
        acc += attn_w[(size_t)j * Hn + k] * ws_h[j];
    __shared__ float p[16][17];
    p[tj][tk] = acc;
    __syncthreads();
    if (t < 16) {
        float s = 0.f;
#pragma unroll
        for (int j = 0; j < 16; ++j) s += p[j][t];
        v[blockIdx.x * 16 + t] = s;
    }
}

// ---------------- K3: scores[s] = enc[s] . v ----------------
__global__ __launch_bounds__(256) void k_scores(const float* __restrict__ enc,
                                                const float* __restrict__ ws_v,
                                                float* __restrict__ scores)
{
    __shared__ float v[Hn];
    const int t = threadIdx.x;
    ((float4*)v)[t] = ((const float4*)ws_v)[t];
    __syncthreads();
    const int wv = t >> 6, lane = t & 63;
    const int s = blockIdx.x * 4 + wv;
    const float* row = enc + (size_t)s * Hn;
    float acc = 0.f;
#pragma unroll
    for (int k = 0; k < 4; ++k) {
        const int idx = k * 256 + lane * 4;
        const float4 e = *(const float4*)(row + idx);
        acc += e.x * v[idx] + e.y * v[idx + 1] + e.z * v[idx + 2] + e.w * v[idx + 3];
    }
    acc = wave_reduce_sum(acc);
    if (lane == 0) scores[s] = acc;
}

// ---------------- K4: softmax (attn_b dropped: shift-invariant) ----------------
__global__ __launch_bounds__(1024) void k_softmax(const float* __restrict__ scores,
                                                  float* __restrict__ attn_ws,
                                                  float* __restrict__ attn_out)
{
    const int t = threadIdx.x;
    const float4 sc = ((const float4*)scores)[t];
    __shared__ float red[16];
    __shared__ float bval;
    const int wv = t >> 6, lane = t & 63;

    float m = fmaxf(fmaxf(sc.x, sc.y), fmaxf(sc.z, sc.w));
#pragma unroll
    for (int o = 32; o > 0; o >>= 1) m = fmaxf(m, __shfl_down(m, o, 64));
    if (lane == 0) red[wv] = m;
    __syncthreads();
    if (t == 0) {
        float mm = red[0];
        for (int i = 1; i < 16; ++i) mm = fmaxf(mm, red[i]);
        bval = mm;
    }
    __syncthreads();
    const float mx = bval;
    const float e0 = expf(sc.x - mx), e1 = expf(sc.y - mx);
    const float e2 = expf(sc.z - mx), e3 = expf(sc.w - mx);
    const float ps = wave_reduce_sum(e0 + e1 + e2 + e3);
    __syncthreads();            // red/bval reads above must complete before reuse
    if (lane == 0) red[wv] = ps;
    __syncthreads();
    if (t == 0) {
        float s = 0.f;
        for (int i = 0; i < 16; ++i) s += red[i];
        bval = 1.f / s;
    }
    __syncthreads();
    const float inv = bval;
    const float4 o4 = make_float4(e0 * inv, e1 * inv, e2 * inv, e3 * inv);
    ((float4*)attn_ws)[t]  = o4;
    ((float4*)attn_out)[t] = o4;
}

// ---------------- K5a: partial context sums ----------------
__global__ __launch_bounds__(256) void k_ctx_part(const float* __restrict__ enc,
                                                  const float* __restrict__ attn,
                                                  float* __restrict__ partial)
{
    const int jc = blockIdx.x & 3;
    const int sc = blockIdx.x >> 2;
    const int j = jc * 256 + threadIdx.x;
    float acc = 0.f;
    const int s0 = sc * 128;
    for (int s = s0; s < s0 + 128; ++s)
        acc += attn[s] * enc[(size_t)s * Hn + j];
    partial[(size_t)sc * Hn + j] = acc;
}

// ---------------- K5b: reduce partials -> context ----------------
__global__ __launch_bounds__(256) void k_ctx_red(const float* __restrict__ partial,
                                                 float* __restrict__ ctx)
{
    const int j = blockIdx.x * 256 + threadIdx.x;
    float acc = 0.f;
#pragma unroll
    for (int sc = 0; sc < 32; ++sc) acc += partial[(size_t)sc * Hn + j];
    ctx[j] = acc;
}

// ---------------- K6: output = out_w . [h, ctx] + out_b ----------------
__global__ __launch_bounds__(256) void k_out(const float* __restrict__ out_w,
                                             const float* __restrict__ out_b,
                                             const float* __restrict__ c2,
                                             float* __restrict__ out)
{
    __shared__ float c[2 * Hn];
    const int t = threadIdx.x;
    ((float4*)c)[t]       = ((const float4*)c2)[t];
    ((float4*)c)[t + 256] = ((const float4*)c2)[t + 256];
    __syncthreads();
    const int wv = t >> 6, lane = t & 63;
    const int row = blockIdx.x * 4 + wv;
    const float* w = out_w + (size_t)row * (2 * Hn);
    float acc = 0.f;
#pragma unroll
    for (int k = 0; k < 8; ++k) {
        const int idx = k * 256 + lane * 4;
        const float4 wv4 = *(const float4*)(w + idx);
        acc += wv4.x * c[idx] + wv4.y * c[idx + 1] + wv4.z * c[idx + 2] + wv4.w * c[idx + 3];
    }
    acc = wave_reduce_sum(acc);
    if (lane == 0) out[row] = acc + out_b[row];
}

extern "C" void kernel_launch(void* const* d_in, const int* in_sizes, int n_in,
                              void* d_out, int out_size, void* d_ws, size_t ws_size,
                              hipStream_t stream) {
    const int*   word   = (const int*)d_in[0];
    const float* h_last = (const float*)d_in[1];
    const float* enc    = (const float*)d_in[2];
    const float* emb    = (const float*)d_in[3];
    const float* w_ih   = (const float*)d_in[4];
    const float* w_hh   = (const float*)d_in[5];
    const float* b_ih   = (const float*)d_in[6];
    const float* b_hh   = (const float*)d_in[7];
    const float* attn_w = (const float*)d_in[8];
    /* d_in[9] attn_b: unused — uniform shift, softmax-invariant */
    const float* out_w  = (const float*)d_in[10];
    const float* out_b  = (const float*)d_in[11];
    float* out = (float*)d_out;
    float* ws  = (float*)d_ws;

    float* ws_h      = ws;          // 1024
    float* ws_ctx    = ws + 1024;   // 1024 (c2 = [h, ctx] contiguous at ws)
    float* ws_v      = ws + 2048;   // 1024
    float* ws_scores = ws + 3072;   // 4096
    float* ws_attn   = ws + 7168;   // 4096
    float* ws_part   = ws + 11264;  // 32*1024

    k_gru<<<Hn, 256, 0, stream>>>(word, emb, h_last, w_ih, w_hh, b_ih, b_hh, ws_h, out + Vn);
    k_attnv<<<Hn / 16, 256, 0, stream>>>(attn_w, ws_h, ws_v);
    k_scores<<<Sn / 4, 256, 0, stream>>>(enc, ws_v, ws_scores);
    k_softmax<<<1, 1024, 0, stream>>>(ws_scores, ws_attn, out + Vn + Hn);
    k_ctx_part<<<128, 256, 0, stream>>>(enc, ws_attn, ws_part);
    k_ctx_red<<<4, 256, 0, stream>>>(ws_part, ws_ctx);
    k_out<<<Vn / 4, 256, 0, stream>>>(out_w, out_b, ws, out);
}